// Round 4
// baseline (23.060 us; speedup 1.0000x reference)
//
#include <hip/hip_runtime.h>

// RefinementCAM: B=4, C=256, H=W=64, N=4096.
// out[b,n] = s[b,n] * (feat[b,:,n] . v[b,:]),
//   v[b,c] = sum_m feat[b,c,m] * w[b,m],  w = s*cam,
//   s = m/max(m*||feat[:,n]||,1e-12).
// K1: norm + per-block v-partials (feat read cold coalesced, then re-read
//     L1/L2-hot in transposed assignment). K2: 512KB partial reduce.
// K3: out pass (feat L3-hot). K4: rescale + loss via last-block atomic.

constexpr int B  = 4;
constexpr int C  = 256;
constexpr int N  = 4096;
constexpr int BN = B * N;       // 16384
constexpr int CN = C * N;
constexpr int NBLK1 = 512;      // K1/K3 blocks (32 pixels each)

__device__ __forceinline__ float wsum(float v) {
#pragma unroll
    for (int o = 32; o > 0; o >>= 1) v += __shfl_down(v, o, 64);
    return v;
}
__device__ __forceinline__ float wmin64(float v) {
#pragma unroll
    for (int o = 32; o > 0; o >>= 1) v = fminf(v, __shfl_down(v, o, 64));
    return v;
}
__device__ __forceinline__ float wmax64(float v) {
#pragma unroll
    for (int o = 32; o > 0; o >>= 1) v = fmaxf(v, __shfl_down(v, o, 64));
    return v;
}

// K1: 512 blocks x 256 thr. Phase 1: channel norms (8 groups x 32 channels,
// coalesced cold read) -> s, w_sh. Phase 2: thread=channel, 32 pixels via
// float4 (L1/L2-hot re-read) -> v_part[blk][c]. Also zeroes loss counter.
__global__ void __launch_bounds__(256) k_norm_vpart(
    const float* __restrict__ cam, const float* __restrict__ feat,
    float* __restrict__ s, float* __restrict__ v_part,
    unsigned int* __restrict__ cnt)
{
    if (blockIdx.x == 0 && threadIdx.x == 0) *cnt = 0u;
    const int t   = threadIdx.x;
    const int pix = t & 31;
    const int g   = t >> 5;          // channel group 0..7
    const int bk  = blockIdx.x;
    const int b   = bk >> 7;         // 128 blocks per batch
    const int n0  = (bk * 32) & (N - 1);

    __shared__ float red[8][33];
    __shared__ float w_sh[32];

    // phase 1: per-pixel channel sum of squares
    {
        const float* fp = feat + (size_t)b * CN + (size_t)(g * 32) * N + n0 + pix;
        float ss = 0.f;
#pragma unroll 8
        for (int cc = 0; cc < 32; ++cc) {
            float x = fp[(size_t)cc * N];     // 32 consecutive lanes -> coalesced
            ss = fmaf(x, x, ss);
        }
        red[g][pix] = ss;
    }
    __syncthreads();
    if (t < 32) {
        float tot = 0.f;
#pragma unroll
        for (int gg = 0; gg < 8; ++gg) tot += red[gg][t];
        float cv = cam[bk * 32 + t];
        float m  = ((cv >= 0.3f ? 1.f : 0.f) + (cv >= 0.4f ? 1.f : 0.f) +
                    (cv >= 0.5f ? 1.f : 0.f)) * (1.f / 3.f);
        float norm = m * sqrtf(tot);          // ||feat*m|| = m*||feat||
        float sc = m / fmaxf(norm, 1e-12f);
        s[bk * 32 + t] = sc;
        w_sh[t] = sc * cv;
    }
    __syncthreads();

    // phase 2: v_part[c] = sum over this block's 32 pixels of feat[c,n]*w[n]
    {
        const float* fp = feat + (size_t)b * CN + (size_t)t * N + n0;
        float acc = 0.f;
#pragma unroll
        for (int pp = 0; pp < 8; ++pp) {
            float4 x = *(const float4*)(fp + pp * 4);
            acc = fmaf(x.x, w_sh[pp * 4 + 0], acc);
            acc = fmaf(x.y, w_sh[pp * 4 + 1], acc);
            acc = fmaf(x.z, w_sh[pp * 4 + 2], acc);
            acc = fmaf(x.w, w_sh[pp * 4 + 3], acc);
        }
        v_part[bk * 256 + t] = acc;           // coalesced
    }
}

// K2: v[b,c] = sum over the batch's 128 block-partials. 4 blocks x 256 thr.
__global__ void __launch_bounds__(256) k_vreduce(
    const float* __restrict__ v_part, float* __restrict__ v)
{
    const int c = threadIdx.x;
    const int b = blockIdx.x;
    const float* base = v_part + (size_t)b * 128 * 256 + c;
    float acc = 0.f;
#pragma unroll 8
    for (int k = 0; k < 128; ++k) acc += base[k * 256];   // coalesced rows
    v[b * 256 + c] = acc;
}

// K3: 512 blocks x 256 thr. ob = s * (feat[:,n].v); per-block min/max.
__global__ void __launch_bounds__(256) k_out(
    const float* __restrict__ feat, const float* __restrict__ s,
    const float* __restrict__ v, float* __restrict__ ob,
    float* __restrict__ bmn, float* __restrict__ bmx)
{
    const int t   = threadIdx.x;
    const int pix = t & 31;
    const int g   = t >> 5;
    const int bk  = blockIdx.x;
    const int b   = bk >> 7;
    const int n0  = (bk * 32) & (N - 1);

    __shared__ float vs[C];
    vs[t] = v[b * C + t];
    __syncthreads();

    const float* fp = feat + (size_t)b * CN + (size_t)(g * 32) * N + n0 + pix;
    float acc = 0.f;
#pragma unroll 8
    for (int cc = 0; cc < 32; ++cc)
        acc = fmaf(fp[(size_t)cc * N], vs[g * 32 + cc], acc);  // vs broadcast

    __shared__ float red[8][33];
    red[g][pix] = acc;
    __syncthreads();
    if (t < 32) {
        float tot = 0.f;
#pragma unroll
        for (int gg = 0; gg < 8; ++gg) tot += red[gg][t];
        float o = s[bk * 32 + t] * tot;
        ob[bk * 32 + t] = o;
        float mn = o, mx = o;
#pragma unroll
        for (int o2 = 16; o2 > 0; o2 >>= 1) {
            mn = fminf(mn, __shfl_down(mn, o2, 64));
            mx = fmaxf(mx, __shfl_down(mx, o2, 64));
        }
        if (t == 0) { bmn[bk] = mn; bmx[bk] = mx; }
    }
}

// K4: 64 blocks x 256 thr. Batch minmax, rescale, |ref-cam|; last block sums loss.
__global__ void __launch_bounds__(256) k_final(
    const float* __restrict__ ob, const float* __restrict__ cam,
    const float* __restrict__ bmn, const float* __restrict__ bmx,
    float* __restrict__ out, float* __restrict__ part, unsigned int* __restrict__ cnt)
{
    const int t = threadIdx.x, blk = blockIdx.x;
    const int p = blk * 256 + t;
    const int b = blk >> 4;                 // 16 blocks per batch

    __shared__ float sh[2];
    if (t < 64) {
        float a = fminf(bmn[b * 128 + t], bmn[b * 128 + 64 + t]);
        a = wmin64(a);
        if (t == 0) sh[0] = a;
    } else if (t < 128) {
        int l = t - 64;
        float a = fmaxf(bmx[b * 128 + l], bmx[b * 128 + 64 + l]);
        a = wmax64(a);
        if (l == 0) sh[1] = a;
    }
    __syncthreads();
    const float mn = sh[0];
    const float mx = sh[1] + 1e-5f;

    float r = (ob[p] - mn) / (mx - mn);
    out[p] = r;
    float ad = fabsf(r - cam[p]);

    __shared__ float red[4];
    float ps = wsum(ad);
    if ((t & 63) == 0) red[t >> 6] = ps;
    __syncthreads();

    __shared__ int lastflag;
    if (t == 0) {
        float tot = (red[0] + red[1]) + (red[2] + red[3]);
        __hip_atomic_store(&part[blk], tot, __ATOMIC_RELEASE, __HIP_MEMORY_SCOPE_AGENT);
        unsigned old = __hip_atomic_fetch_add(cnt, 1u, __ATOMIC_ACQ_REL,
                                              __HIP_MEMORY_SCOPE_AGENT);
        lastflag = (old == 63u) ? 1 : 0;
    }
    __syncthreads();
    if (lastflag && t < 64) {
        float x = __hip_atomic_load(&part[t], __ATOMIC_ACQUIRE,
                                    __HIP_MEMORY_SCOPE_AGENT);
        x = wsum(x);                        // fixed-order: deterministic
        if (t == 0) out[BN] = x * (1.f / (float)BN);
    }
}

extern "C" void kernel_launch(void* const* d_in, const int* in_sizes, int n_in,
                              void* d_out, int out_size, void* d_ws, size_t ws_size,
                              hipStream_t stream) {
    const float* cam  = (const float*)d_in[0];   // (4,64,64)
    const float* feat = (const float*)d_in[1];   // (4,256,64,64)
    float* out = (float*)d_out;                  // [16384 ref][1 loss]
    float* ws  = (float*)d_ws;

    float* s      = ws;                   // 16384
    float* v_part = ws + 16384;           // 512*256 = 131072
    float* v      = ws + 147456;          // 1024
    float* ob     = ws + 148480;          // 16384
    float* bmn    = ws + 164864;          // 512
    float* bmx    = ws + 165376;          // 512
    float* part   = ws + 165888;          // 64
    unsigned int* cnt = (unsigned int*)(ws + 165952);

    k_norm_vpart<<<NBLK1, 256, 0, stream>>>(cam, feat, s, v_part, cnt);
    k_vreduce   <<<B,     256, 0, stream>>>(v_part, v);
    k_out       <<<NBLK1, 256, 0, stream>>>(feat, s, v, ob, bmn, bmx);
    k_final     <<<64,    256, 0, stream>>>(ob, cam, bmn, bmx, out, part, cnt);
}